// Round 7
// baseline (1397.905 us; speedup 1.0000x reference)
//
#include <hip/hip_runtime.h>
#include <hip/hip_bf16.h>

// SwiGLU MLP: out = down( silu(x@Wg^T + bg) * (x@Wu^T + bu) ) + bd
// M=4096 tokens, H=4096, I=11008. fp32 in/out, bf16 MFMA compute.
// GEMM: 256x128 tile, BK=32, 8 waves (4Mx2N, 64x64/wave), 3-deep LDS ring
// (72 KiB -> 2 blocks/CU, 4 waves/SIMD), counted vmcnt(3), 1 barrier/tile,
// XOR-swizzled LDS, XCD-aware bijective block swizzle.

#define M_TOK 4096
#define HID   4096
#define INT_  11008

typedef __attribute__((ext_vector_type(8))) short bf16x8;
typedef __attribute__((ext_vector_type(4))) float f32x4;

__device__ __forceinline__ unsigned short f2bf(float f) {
    union { float f; unsigned int u; } a; a.f = f;
    unsigned int u = a.u;
    u += 0x7fff + ((u >> 16) & 1);   // RNE
    return (unsigned short)(u >> 16);
}

__device__ __forceinline__ float bf2f(unsigned short h) {
    union { unsigned int u; float f; } a; a.u = ((unsigned int)h) << 16;
    return a.f;
}

// ---------------- fp32 -> bf16 convert (vectorized, grid-stride) ----------------
__global__ void cvt_f32_bf16(const float* __restrict__ in, unsigned short* __restrict__ out, int n4) {
    int stride = gridDim.x * blockDim.x;
    for (int i = blockIdx.x * blockDim.x + threadIdx.x; i < n4; i += stride) {
        float4 v = ((const float4*)in)[i];
        ushort4 o;
        o.x = f2bf(v.x); o.y = f2bf(v.y); o.z = f2bf(v.z); o.w = f2bf(v.w);
        ((ushort4*)out)[i] = o;
    }
}

#define GLL(gsrc, ldst) \
    __builtin_amdgcn_global_load_lds( \
        (__attribute__((address_space(1))) void*)(gsrc), \
        (__attribute__((address_space(3))) void*)(ldst), 16, 0, 0)

// ---------------- 256x128-tile bf16 GEMM, C = A * B^T (+epilogue) ----------------
// A: M x K bf16 row-major; B: N x K bf16 row-major. M%256==0, N%128==0, K%32==0,
// K/32 >= 3, grid divisible by 8.
// LDS ring: 3 buffers x (A 256x32 = 16KB + B 128x32 = 8KB) = 72 KiB.
// EPI 0: bf16 (acc+bias); EPI 1: bf16 silu(g)*(acc+bias); EPI 2: fp32 (acc+bias)
template<int EPI>
__global__ __launch_bounds__(512, 4)
void gemm256(const unsigned short* __restrict__ A,
             const unsigned short* __restrict__ B,
             const float* __restrict__ bias,
             const unsigned short* __restrict__ gbuf,
             void* __restrict__ Cv,
             int M, int N, int K) {
    __shared__ unsigned short lds[3 * 12288];   // 72 KiB, 3 K-tile ring

    const int tid  = threadIdx.x;
    const int lane = tid & 63;
    const int w    = tid >> 6;       // wave 0..7
    const int wm   = w >> 1;         // 0..3  (M quarter, 64 rows)
    const int wn   = w & 1;          // 0..1  (N half, 64 cols)

    // XCD-aware bijective swizzle (grid % 8 == 0)
    const int ntn = N >> 7;
    const int chunk = gridDim.x >> 3;
    const int sw = (blockIdx.x & 7) * chunk + (blockIdx.x >> 3);
    const int bm = sw / ntn, bn = sw % ntn;

    // ---- staging source decode (inverse swizzle; LDS dest stays linear) ----
    // A: 1024 16B-slots (2 GLL, lp = i*512+tid); B: 512 slots (1 GLL, lp = tid)
    size_t gOfs[2];
#pragma unroll
    for (int i = 0; i < 2; ++i) {
        int lp  = i * 512 + tid;
        int pr  = lp >> 2, ps = lp & 3;
        int row = pr ^ ((pr >> 2) & 1);      // logical row (involution)
        int s   = ps ^ (row & 3);            // logical 16B slot within row
        gOfs[i] = (size_t)row * K + s * 8;
    }
    const unsigned short* Ag = A + (size_t)(bm * 256) * K;
    const unsigned short* Bg = B + (size_t)(bn * 128) * K;

    // ---- ds_read fragment addresses (swizzled) ----
    const int ar  = lane & 15;
    const int kg  = lane >> 4;
    const int rsw = ar ^ ((ar >> 2) & 1);
    const int ssw = (kg ^ (ar & 3)) * 8;
    const int aoff = (wm * 64 + rsw) * 32 + ssw;           // + m*512
    const int boff = 8192 + (wn * 64 + rsw) * 32 + ssw;    // + n*512

    f32x4 acc[4][4];
#pragma unroll
    for (int m = 0; m < 4; ++m)
#pragma unroll
        for (int n = 0; n < 4; ++n)
            acc[m][n] = (f32x4){0.f, 0.f, 0.f, 0.f};

    const int NT = K >> 5;

    // staging dest offsets (wave-uniform base + lane*16B, linear)
    const int dA = w * 512;          // + i*4096 for A's two GLL
    const int dB = 8192 + w * 512;   // B's single GLL

    // ---- prologue: stage K-tiles 0,1 into slots 0,1 ----
#pragma unroll
    for (int tt = 0; tt < 2; ++tt) {
        unsigned short* base = lds + tt * 12288;
        const unsigned short* sA = Ag + tt * 32;
        const unsigned short* sB = Bg + tt * 32;
        GLL(sA + gOfs[0], base + dA);
        GLL(sA + gOfs[1], base + dA + 4096);
        GLL(sB + gOfs[0], base + dB);
    }
    asm volatile("s_waitcnt vmcnt(3)" ::: "memory");   // tile 0 landed (1 in flight)
    __builtin_amdgcn_s_barrier();

    // ---- main loop: read frags | stage t+2 | 16 MFMA | vmcnt(3) | barrier ----
    for (int t = 0; t < NT; ++t) {
        const unsigned short* bufc = lds + (t % 3) * 12288;
        const int ts = (t + 2 < NT) ? (t + 2) : (NT - 1);   // clamped tail re-stage
        unsigned short* dS = lds + ((t + 2) % 3) * 12288;
        const unsigned short* sA = Ag + (size_t)ts * 32;
        const unsigned short* sB = Bg + (size_t)ts * 32;

        bf16x8 a_[4], b_[4];
#pragma unroll
        for (int m = 0; m < 4; ++m) a_[m] = *(const bf16x8*)(bufc + aoff + m * 512);
#pragma unroll
        for (int n = 0; n < 4; ++n) b_[n] = *(const bf16x8*)(bufc + boff + n * 512);
        GLL(sA + gOfs[0], dS + dA);
        GLL(sA + gOfs[1], dS + dA + 4096);
        GLL(sB + gOfs[0], dS + dB);
        __builtin_amdgcn_s_setprio(1);
#pragma unroll
        for (int m = 0; m < 4; ++m)
#pragma unroll
            for (int n = 0; n < 4; ++n)
                acc[m][n] = __builtin_amdgcn_mfma_f32_16x16x32_bf16(a_[m], b_[n], acc[m][n], 0, 0, 0);
        __builtin_amdgcn_s_setprio(0);
        // own t+1 loads landed (t+2's 3 stay in flight); all slot-t reads were
        // MFMA-consumed above, so no lgkm drain needed before the barrier.
        asm volatile("s_waitcnt vmcnt(3)" ::: "memory");
        __builtin_amdgcn_s_barrier();
    }

    // ---- epilogue: C/D layout col=lane&15, row=(lane>>4)*4+j  [m89-verified] ----
    const int row0 = bm * 256 + wm * 64 + (lane >> 4) * 4;
    const int col0 = bn * 128 + wn * 64 + (lane & 15);
#pragma unroll
    for (int n = 0; n < 4; ++n) {
        const int col = col0 + n * 16;
        const float bv = bias[col];
#pragma unroll
        for (int m = 0; m < 4; ++m) {
            const int rb = row0 + m * 16;
#pragma unroll
            for (int j = 0; j < 4; ++j) {
                const size_t idx = (size_t)(rb + j) * (size_t)N + col;
                float v = acc[m][n][j] + bv;
                if (EPI == 0) {
                    ((unsigned short*)Cv)[idx] = f2bf(v);
                } else if (EPI == 1) {
                    float g = bf2f(gbuf[idx]);
                    float s = g / (1.f + __expf(-g));   // silu(g)
                    ((unsigned short*)Cv)[idx] = f2bf(s * v);
                } else {
                    ((float*)Cv)[idx] = v;
                }
            }
        }
    }
}

// ---------------- launcher ----------------
extern "C" void kernel_launch(void* const* d_in, const int* in_sizes, int n_in,
                              void* d_out, int out_size, void* d_ws, size_t ws_size,
                              hipStream_t stream) {
    const float* x  = (const float*)d_in[0];   // (2,2048,4096)
    const float* wg = (const float*)d_in[1];   // (11008,4096)
    const float* bg = (const float*)d_in[2];
    const float* wu = (const float*)d_in[3];
    const float* bu = (const float*)d_in[4];
    const float* wd = (const float*)d_in[5];   // (4096,11008)
    const float* bd = (const float*)d_in[6];

    const size_t NX = (size_t)M_TOK * HID;     // 16,777,216
    const size_t NW = (size_t)INT_ * HID;      // 45,088,768 (== M_TOK*INT_)

    unsigned short* ws = (unsigned short*)d_ws;
    unsigned short* Xb = ws;                   // x bf16
    unsigned short* S1 = Xb + NX;              // Wg -> later t
    unsigned short* S2 = S1 + NW;              // g  -> later Wd
    unsigned short* S3 = S2 + NW;              // Wu
    // peak ws need: (NX + 3*NW)*2 = 304,087,040 bytes

    dim3 blk512(512);
    dim3 blk256(256);
    const int CG = 2048;

    cvt_f32_bf16<<<CG, blk256, 0, stream>>>(x,  Xb, (int)(NX / 4));
    cvt_f32_bf16<<<CG, blk256, 0, stream>>>(wg, S1, (int)(NW / 4));
    // gate: g = x @ Wg^T + bg  (bf16 -> S2)   grid 16*86=1376 (%8==0)
    gemm256<0><<<dim3(16 * 86), blk512, 0, stream>>>(Xb, S1, bg, (const unsigned short*)nullptr,
                                                     (void*)S2, M_TOK, INT_, HID);
    cvt_f32_bf16<<<CG, blk256, 0, stream>>>(wu, S3, (int)(NW / 4));
    // up + fuse: t = silu(g) * (x @ Wu^T + bu)  (bf16 -> S1, Wg dead)
    gemm256<1><<<dim3(16 * 86), blk512, 0, stream>>>(Xb, S3, bu, S2,
                                                     (void*)S1, M_TOK, INT_, HID);
    cvt_f32_bf16<<<CG, blk256, 0, stream>>>(wd, S2, (int)(NW / 4));
    // down: out = t @ Wd^T + bd  (fp32 -> d_out)  grid 16*32=512 (%8==0)
    gemm256<2><<<dim3(16 * 32), blk512, 0, stream>>>(S1, S2, bd, (const unsigned short*)nullptr,
                                                     d_out, M_TOK, HID, INT_);
}